// Round 3
// baseline (1429.280 us; speedup 1.0000x reference)
//
#include <hip/hip_runtime.h>
#include <cmath>

namespace {

constexpr int XC = 64, XH = 128, XW = 128;
constexpr int NSEQ = 128;   // B(2) * 64 cubes
constexpr int TLEN = 1025;  // gt token + 1024
constexpr int NCH = 16;     // chunks per sequence
constexpr int CHUNK = 65;   // 16*65 = 1040 >= 1025

__device__ __forceinline__ int xidx(int b, int c, int h, int w) {
    return ((b * XC + c) * XH + h) * XW + w;
}
__device__ __forceinline__ int oidx(int b, int cube, int c, int i, int j) {
    int h = cube * 2 + (i >> 3);
    int w = ((i & 7) << 4) | j;
    return xidx(b, c, h, w);
}
__device__ __forceinline__ float siluf(float v) { return v / (1.0f + __expf(-v)); }
__device__ __forceinline__ float softplusf(float v) {
    return v > 20.0f ? v : log1pf(__expf(v));
}

// Gather one element of the LN input: token t (global), lane k in [0,16).
template <int MODE>
__device__ __forceinline__ float gather_val(const float* __restrict__ x,
                                            const float* __restrict__ s_gt,
                                            int t, int k, int b, int bi, int bj) {
    if (t == 0) return s_gt[k];
    int l = t - 1;
    if (MODE == 0) {
        int i2 = l >> 5, j2 = l & 31;
        int h = bi * 16 + (i2 >> 1), w = bj * 16 + (j2 >> 1);
        int coff = ((i2 & 1) << 1) | (j2 & 1);
        return x[xidx(b, k * 4 + coff, h, w)];
    } else if (MODE == 1) {
        int c = l >> 4, j = l & 15;
        return x[xidx(b, c, bi * 16 + k, bj * 16 + j)];
    } else {
        int c = l >> 4, i = l & 15;
        return x[xidx(b, c, bi * 16 + i, bj * 16 + k)];
    }
}

// ================= kernel A: fused front-end + chunk scan pass 1 =============
template <int MODE>
__global__ __launch_bounds__(512) void k_fs1(
    const float* __restrict__ x, const float* __restrict__ gt,
    const float* __restrict__ lng, const float* __restrict__ lnb,
    const float* __restrict__ in_w,   // (64,16), rows 0..31 = xi
    const float* __restrict__ conv_w, // (32,4)
    const float* __restrict__ conv_b, // (32)
    const float* __restrict__ xproj_w,// (33,32)
    const float* __restrict__ dt_w,   // (32,1)
    const float* __restrict__ dt_b,   // (32)
    const float* __restrict__ A_log,  // (32,16)
    float* __restrict__ Psum, float* __restrict__ Fsum)
{
    const int n = blockIdx.x >> 4, ch = blockIdx.x & (NCH - 1);
    const int t0 = ch * CHUNK;
    const int nt = min(CHUNK, TLEN - t0);
    const int nth = nt + 3;
    const int b = n >> 6, cube = n & 63, bi = cube >> 3, bj = cube & 7;
    const int tid = threadIdx.x;

    __shared__ float s_v[68][17];
    __shared__ float s_xi[68][33];
    __shared__ float s_xc[CHUNK][33];
    __shared__ float s_B[CHUNK][17];
    __shared__ float s_dt0[CHUNK];
    __shared__ float s_wT[16][32];    // in_w rows 0..31 transposed
    __shared__ float s_xp[17][33];    // xproj rows 0..16 (0=dt0, 1..16=B), padded
    __shared__ float s_cw[128], s_cb[32], s_gt[16], s_g[16], s_bb[16];

    // ---- weights / consts
    for (int i = tid; i < 32 * 16; i += 512) s_wT[i & 15][i >> 4] = in_w[i];
    for (int i = tid; i < 17 * 32; i += 512) s_xp[i >> 5][i & 31] = xproj_w[i];
    if (tid < 128) s_cw[tid] = conv_w[tid];
    if (tid < 32) s_cb[tid] = conv_b[tid];
    if (tid < 16) { s_gt[tid] = gt[tid]; s_g[tid] = lng[tid]; s_bb[tid] = lnb[tid]; }
    const float A = -__expf(A_log[tid]);
    const float dw_d = dt_w[tid >> 4], db_d = dt_b[tid >> 4];
    __syncthreads();

    // ---- gather raw tokens (halo included)
    for (int it = tid; it < nth * 16; it += 512) {
        int tl = it >> 4, k = it & 15;
        int t = t0 - 3 + tl;
        s_v[tl][k] = (t < 0) ? 0.f : gather_val<MODE>(x, s_gt, t, k, b, bi, bj);
    }
    __syncthreads();

    // ---- layernorm (per token)
    for (int tl = tid; tl < nth; tl += 512) {
        int t = t0 - 3 + tl;
        if (t < 0) continue;
        float v[16], mu = 0.f;
#pragma unroll
        for (int k = 0; k < 16; k++) { v[k] = s_v[tl][k]; mu += v[k]; }
        mu *= (1.f / 16.f);
        float var = 0.f;
#pragma unroll
        for (int k = 0; k < 16; k++) { float d = v[k] - mu; var += d * d; }
        float inv = rsqrtf(var * (1.f / 16.f) + 1e-5f);
#pragma unroll
        for (int k = 0; k < 16; k++) s_v[tl][k] = (v[k] - mu) * inv * s_g[k] + s_bb[k];
    }
    __syncthreads();

    // ---- in-proj (xi half only)
    for (int it = tid; it < nth * 32; it += 512) {
        int tl = it >> 5, oc = it & 31;
        int t = t0 - 3 + tl;
        float acc = 0.f;
        if (t >= 0) {
#pragma unroll
            for (int k = 0; k < 16; k++) acc += s_v[tl][k] * s_wT[k][oc];
        }
        s_xi[tl][oc] = acc;
    }
    __syncthreads();

    // ---- causal conv4 + silu
    for (int it = tid; it < nt * 32; it += 512) {
        int j = it >> 5, cc = it & 31;
        float acc = s_cb[cc];
#pragma unroll
        for (int k = 0; k < 4; k++) acc += s_cw[cc * 4 + k] * s_xi[j + k][cc];
        s_xc[j][cc] = siluf(acc);
    }
    __syncthreads();

    // ---- x-proj rows 0..16 (dt0 + B)
    for (int it = tid; it < 17 * nt; it += 512) {
        int r = it / nt, j = it - r * nt;
        float acc = 0.f;
#pragma unroll
        for (int cc = 0; cc < 32; cc++) acc += s_xc[j][cc] * s_xp[r][cc];
        if (r == 0) s_dt0[j] = acc;
        else s_B[j][r - 1] = acc;
    }
    __syncthreads();

    // ---- chunk scan pass 1 (P = prod a, F = h from 0)
    const int d = tid >> 4, s = tid & 15;
    float h = 0.f, P = 1.f;
    for (int t = 0; t < nt; t++) {
        float dt = softplusf(s_dt0[t] * dw_d + db_d);
        float a = __expf(dt * A);
        h = a * h + dt * s_B[t][s] * s_xc[t][d];
        P *= a;
    }
    size_t idx = ((size_t)n * NCH + ch) * 512 + tid;
    Psum[idx] = P;
    Fsum[idx] = h;
}

// ================= combine chunk summaries -> incoming state ================
__global__ __launch_bounds__(512) void k_comb(const float* __restrict__ Psum,
                                              const float* __restrict__ Fsum,
                                              float* __restrict__ Hin)
{
    int n = blockIdx.x, tid = threadIdx.x;
    const float* pb = Psum + (size_t)n * NCH * 512;
    const float* fb = Fsum + (size_t)n * NCH * 512;
    float* hb = Hin + (size_t)n * NCH * 512;
    float H = 0.f;
#pragma unroll
    for (int c = 0; c < NCH; c++) {
        float P = pb[(size_t)c * 512 + tid];
        float F = fb[(size_t)c * 512 + tid];
        hb[(size_t)c * 512 + tid] = H;
        H = F + P * H;
    }
}

// ====== kernel C: front-end + scan pass 2 + gate + out-proj + scatter =======
template <int MODE>
__global__ __launch_bounds__(512) void k_fs2(
    const float* __restrict__ x, const float* __restrict__ gt,
    const float* __restrict__ lng, const float* __restrict__ lnb,
    const float* __restrict__ in_w,   // (64,16)
    const float* __restrict__ conv_w, const float* __restrict__ conv_b,
    const float* __restrict__ xproj_w,// (33,32)
    const float* __restrict__ dt_w, const float* __restrict__ dt_b,
    const float* __restrict__ A_log, const float* __restrict__ Dp,
    const float* __restrict__ out_w,  // (16,32)
    const float* __restrict__ Hin,
    float* __restrict__ out)
{
    const int n = blockIdx.x >> 4, ch = blockIdx.x & (NCH - 1);
    const int t0 = ch * CHUNK;
    const int nt = min(CHUNK, TLEN - t0);
    const int nth = nt + 3;
    const int b = n >> 6, cube = n & 63, bi = cube >> 3, bj = cube & 7;
    const int tid = threadIdx.x;

    __shared__ float s_v[68][17];
    __shared__ float s_xz[68][65];    // 0..31 xi, 32..63 z
    __shared__ float s_xc[CHUNK][33]; // xc, overwritten by y then gated y
    __shared__ float s_B[CHUNK][17];
    __shared__ float s_C[CHUNK][17];
    __shared__ float s_dt0[CHUNK];
    __shared__ float s_wT[16][64];    // in_w transposed, all 64 rows
    __shared__ float s_xp[33][33];    // all xproj rows, padded
    __shared__ float s_owT[32][17];   // out_w transposed
    __shared__ float s_cw[128], s_cb[32], s_gt[16], s_g[16], s_bb[16];

    for (int i = tid; i < 64 * 16; i += 512) s_wT[i & 15][i >> 4] = in_w[i];
    for (int i = tid; i < 33 * 32; i += 512) s_xp[i >> 5][i & 31] = xproj_w[i];
    for (int i = tid; i < 16 * 32; i += 512) s_owT[i & 31][i >> 5] = out_w[i];
    if (tid < 128) s_cw[tid] = conv_w[tid];
    if (tid < 32) s_cb[tid] = conv_b[tid];
    if (tid < 16) { s_gt[tid] = gt[tid]; s_g[tid] = lng[tid]; s_bb[tid] = lnb[tid]; }
    const float A = -__expf(A_log[tid]);
    const float dw_d = dt_w[tid >> 4], db_d = dt_b[tid >> 4];
    const float Dd = Dp[tid >> 4];
    __syncthreads();

    for (int it = tid; it < nth * 16; it += 512) {
        int tl = it >> 4, k = it & 15;
        int t = t0 - 3 + tl;
        s_v[tl][k] = (t < 0) ? 0.f : gather_val<MODE>(x, s_gt, t, k, b, bi, bj);
    }
    __syncthreads();

    for (int tl = tid; tl < nth; tl += 512) {
        int t = t0 - 3 + tl;
        if (t < 0) continue;
        float v[16], mu = 0.f;
#pragma unroll
        for (int k = 0; k < 16; k++) { v[k] = s_v[tl][k]; mu += v[k]; }
        mu *= (1.f / 16.f);
        float var = 0.f;
#pragma unroll
        for (int k = 0; k < 16; k++) { float d = v[k] - mu; var += d * d; }
        float inv = rsqrtf(var * (1.f / 16.f) + 1e-5f);
#pragma unroll
        for (int k = 0; k < 16; k++) s_v[tl][k] = (v[k] - mu) * inv * s_g[k] + s_bb[k];
    }
    __syncthreads();

    // in-proj, all 64 outputs (xi + z)
    for (int it = tid; it < nth * 64; it += 512) {
        int tl = it >> 6, oc = it & 63;
        int t = t0 - 3 + tl;
        float acc = 0.f;
        if (t >= 0) {
#pragma unroll
            for (int k = 0; k < 16; k++) acc += s_v[tl][k] * s_wT[k][oc];
        }
        s_xz[tl][oc] = acc;
    }
    __syncthreads();

    for (int it = tid; it < nt * 32; it += 512) {
        int j = it >> 5, cc = it & 31;
        float acc = s_cb[cc];
#pragma unroll
        for (int k = 0; k < 4; k++) acc += s_cw[cc * 4 + k] * s_xz[j + k][cc];
        s_xc[j][cc] = siluf(acc);
    }
    __syncthreads();

    // x-proj rows 0..32 (dt0, B, C)
    for (int it = tid; it < 33 * nt; it += 512) {
        int r = it / nt, j = it - r * nt;
        float acc = 0.f;
#pragma unroll
        for (int cc = 0; cc < 32; cc++) acc += s_xc[j][cc] * s_xp[r][cc];
        if (r == 0) s_dt0[j] = acc;
        else if (r <= 16) s_B[j][r - 1] = acc;
        else s_C[j][r - 17] = acc;
    }
    __syncthreads();

    // scan pass 2 with true incoming state; y overwrites s_xc in place
    const int d = tid >> 4, s = tid & 15;
    float h = Hin[((size_t)n * NCH + ch) * 512 + tid];
    for (int t = 0; t < nt; t++) {
        float dt = softplusf(s_dt0[t] * dw_d + db_d);
        float xcv = s_xc[t][d];
        float a = __expf(dt * A);
        h = a * h + dt * s_B[t][s] * xcv;
        float pp = h * s_C[t][s];
        pp += __shfl_xor(pp, 1);
        pp += __shfl_xor(pp, 2);
        pp += __shfl_xor(pp, 4);
        pp += __shfl_xor(pp, 8);
        if (s == 0) s_xc[t][d] = pp + Dd * xcv;  // same wave owns (t,d): safe
    }
    __syncthreads();

    // gate with silu(z)
    for (int it = tid; it < nt * 32; it += 512) {
        int j = it >> 5, cc = it & 31;
        s_xc[j][cc] *= siluf(s_xz[j + 3][32 + cc]);
    }
    __syncthreads();

    // out-proj + scatter
    for (int it = tid; it < nt * 16; it += 512) {
        int j = it >> 4, oj = it & 15;
        int t = t0 + j;
        if (t == 0) continue;  // gt token dropped
        int l = t - 1;
        float acc = 0.f;
#pragma unroll
        for (int cc = 0; cc < 32; cc++) acc += s_xc[j][cc] * s_owT[cc][oj];
        acc *= (1.f / 3.f);
        if (MODE == 0) {
            int i2 = l >> 5, j2 = l & 31;
            int io = i2 >> 1, jo = j2 >> 1;
            int coff = ((i2 & 1) << 1) | (j2 & 1);
            out[oidx(b, cube, oj * 4 + coff, io, jo)] = acc;
        } else if (MODE == 1) {
            int c = l >> 4, jj = l & 15;
            out[oidx(b, cube, c, oj, jj)] += acc;
        } else {
            int c = l >> 4, ii = l & 15;
            out[oidx(b, cube, c, ii, oj)] += acc;
        }
    }
}

}  // namespace

extern "C" void kernel_launch(void* const* d_in, const int* in_sizes, int n_in,
                              void* d_out, int out_size, void* d_ws, size_t ws_size,
                              hipStream_t stream) {
    const float* x   = (const float*)d_in[0];
    const float* gt1 = (const float*)d_in[1];
    const float* gt2 = (const float*)d_in[2];
    const float* ln1g = (const float*)d_in[3];
    const float* ln1b = (const float*)d_in[4];
    const float* ln2g = (const float*)d_in[5];
    const float* ln2b = (const float*)d_in[6];
    const float* m[2][9];
    for (int mi = 0; mi < 2; mi++)
        for (int k = 0; k < 9; k++) m[mi][k] = (const float*)d_in[7 + mi * 9 + k];
    float* out = (float*)d_out;

    float* ws = (float*)d_ws;
    float* PS = ws;                               // 128*16*512 f32 (4.2 MB)
    float* FS = PS + (size_t)NSEQ * NCH * 512;
    float* HI = FS + (size_t)NSEQ * NCH * 512;

    dim3 gscan(NSEQ * NCH), bscan(512);

    for (int mode = 0; mode < 3; mode++) {
        int pi = (mode == 0) ? 0 : 1;
        const float* gt = (mode == 0) ? gt1 : gt2;
        const float* lg = (mode == 0) ? ln1g : ln2g;
        const float* lb = (mode == 0) ? ln1b : ln2b;
        const float* const* P = m[pi];
        // P: 0 in_w, 1 conv_w, 2 conv_b, 3 xproj_w, 4 dt_w, 5 dt_b, 6 A_log, 7 D, 8 out_w
        if (mode == 0)
            k_fs1<0><<<gscan, bscan, 0, stream>>>(x, gt, lg, lb, P[0], P[1], P[2], P[3], P[4], P[5], P[6], PS, FS);
        else if (mode == 1)
            k_fs1<1><<<gscan, bscan, 0, stream>>>(x, gt, lg, lb, P[0], P[1], P[2], P[3], P[4], P[5], P[6], PS, FS);
        else
            k_fs1<2><<<gscan, bscan, 0, stream>>>(x, gt, lg, lb, P[0], P[1], P[2], P[3], P[4], P[5], P[6], PS, FS);
        k_comb<<<dim3(NSEQ), bscan, 0, stream>>>(PS, FS, HI);
        if (mode == 0)
            k_fs2<0><<<gscan, bscan, 0, stream>>>(x, gt, lg, lb, P[0], P[1], P[2], P[3], P[4], P[5], P[6], P[7], P[8], HI, out);
        else if (mode == 1)
            k_fs2<1><<<gscan, bscan, 0, stream>>>(x, gt, lg, lb, P[0], P[1], P[2], P[3], P[4], P[5], P[6], P[7], P[8], HI, out);
        else
            k_fs2<2><<<gscan, bscan, 0, stream>>>(x, gt, lg, lb, P[0], P[1], P[2], P[3], P[4], P[5], P[6], P[7], P[8], HI, out);
    }
}

// Round 4
// 614.102 us; speedup vs baseline: 2.3274x; 2.3274x over previous
//
#include <hip/hip_runtime.h>
#include <cmath>

namespace {

constexpr int XC = 64, XH = 128, XW = 128;
constexpr int NSEQ = 128;   // B(2) * 64 cubes
constexpr int TLEN = 1025;  // gt token + 1024
constexpr int LSEQ = 1024;
constexpr int NCH = 16;     // chunks per sequence (parallel scan)
constexpr int CHUNK = 65;   // 16*65 = 1040 >= 1025
constexpr int TT = 128;     // token tile for p1a/p1b
constexpr int NT = 9;       // ceil(1025/128)

__device__ __forceinline__ int xidx(int b, int c, int h, int w) {
    return ((b * XC + c) * XH + h) * XW + w;
}
__device__ __forceinline__ int oidx(int b, int cube, int c, int i, int j) {
    int h = cube * 2 + (i >> 3);
    int w = ((i & 7) << 4) | j;
    return xidx(b, c, h, w);
}
__device__ __forceinline__ float siluf(float v) { return v / (1.0f + __expf(-v)); }
__device__ __forceinline__ float softplusf(float v) {
    return v > 20.0f ? v : log1pf(__expf(v));
}

template <int MODE>
__device__ __forceinline__ float gather_val(const float* __restrict__ x,
                                            const float* __restrict__ s_gt,
                                            int t, int k, int b, int bi, int bj) {
    if (t == 0) return s_gt[k];
    int l = t - 1;
    if (MODE == 0) {
        int i2 = l >> 5, j2 = l & 31;
        int h = bi * 16 + (i2 >> 1), w = bj * 16 + (j2 >> 1);
        int coff = ((i2 & 1) << 1) | (j2 & 1);
        return x[xidx(b, k * 4 + coff, h, w)];
    } else if (MODE == 1) {
        int c = l >> 4, j = l & 15;
        return x[xidx(b, c, bi * 16 + k, bj * 16 + j)];
    } else {
        int c = l >> 4, i = l & 15;
        return x[xidx(b, c, bi * 16 + i, bj * 16 + k)];
    }
}

// ======= phase 1a (tiled): gather + LN + in-proj, coalesced stores ==========
template <int MODE>
__global__ __launch_bounds__(256) void k_p1a(
    const float* __restrict__ x, const float* __restrict__ gt,
    const float* __restrict__ lng, const float* __restrict__ lnb,
    const float* __restrict__ in_w,  // (64,16)
    float* __restrict__ XI,          // (NSEQ,TLEN,32)
    float* __restrict__ Zb)          // (NSEQ,TLEN,32)
{
    const int n = blockIdx.x / NT, tile = blockIdx.x % NT;
    const int t0 = tile * TT;
    const int ntk = min(TT, TLEN - t0);
    const int b = n >> 6, cube = n & 63, bi = cube >> 3, bj = cube & 7;
    const int tid = threadIdx.x;

    __shared__ float s_v[TT][17];
    __shared__ float s_wT[16][64];
    __shared__ float s_g[16], s_bb[16], s_gt[16];

    for (int i = tid; i < 64 * 16; i += 256) s_wT[i & 15][i >> 4] = in_w[i];
    if (tid < 16) { s_g[tid] = lng[tid]; s_bb[tid] = lnb[tid]; s_gt[tid] = gt[tid]; }
    __syncthreads();

    for (int it = tid; it < ntk * 16; it += 256) {
        int tl = it >> 4, k = it & 15;
        s_v[tl][k] = gather_val<MODE>(x, s_gt, t0 + tl, k, b, bi, bj);
    }
    __syncthreads();

    if (tid < ntk) {
        float v[16], mu = 0.f;
#pragma unroll
        for (int k = 0; k < 16; k++) { v[k] = s_v[tid][k]; mu += v[k]; }
        mu *= (1.f / 16.f);
        float var = 0.f;
#pragma unroll
        for (int k = 0; k < 16; k++) { float d = v[k] - mu; var += d * d; }
        float inv = rsqrtf(var * (1.f / 16.f) + 1e-5f);
#pragma unroll
        for (int k = 0; k < 16; k++) s_v[tid][k] = (v[k] - mu) * inv * s_g[k] + s_bb[k];
    }
    __syncthreads();

    // in-proj: it = token*64 + oc  -> contiguous wave stores
    for (int it = tid; it < ntk * 64; it += 256) {
        int tl = it >> 6, oc = it & 63;
        float acc = 0.f;
#pragma unroll
        for (int k = 0; k < 16; k++) acc += s_v[tl][k] * s_wT[k][oc];
        size_t base = ((size_t)n * TLEN + t0 + tl) * 32;
        if (oc < 32) XI[base + oc] = acc;
        else         Zb[base + oc - 32] = acc;
    }
}

// ======= phase 1b (tiled): conv4 + silu + x-proj + dt, coalesced stores =====
__global__ __launch_bounds__(256) void k_p1b(
    const float* __restrict__ XI,
    const float* __restrict__ conv_w,  // (32,4)
    const float* __restrict__ conv_b,  // (32)
    const float* __restrict__ xproj_w, // (33,32)
    const float* __restrict__ dt_w,    // (32,1)
    const float* __restrict__ dt_b,    // (32)
    float* __restrict__ sc)            // (NSEQ,TLEN,96): xc[32] dt[32] B[16] C[16]
{
    const int n = blockIdx.x / NT, tile = blockIdx.x % NT;
    const int t0 = tile * TT;
    const int ntk = min(TT, TLEN - t0);
    const int tid = threadIdx.x;

    __shared__ float s_xi[TT + 3][36];
    __shared__ float s_xc[TT][36];
    __shared__ float s_dt0[TT];
    __shared__ float s_xp[33][33];
    __shared__ float s_cw[128], s_cb[32], s_dw[32], s_db[32];

    for (int i = tid; i < 33 * 32; i += 256) s_xp[i >> 5][i & 31] = xproj_w[i];
    if (tid < 128) s_cw[tid] = conv_w[tid];
    if (tid < 32) {
        s_cb[tid] = conv_b[tid];
        s_dw[tid] = dt_w[tid];
        s_db[tid] = dt_b[tid];
    }

    // load xi tile + 3-token halo (float4, coalesced)
    const float* xin = XI + ((size_t)n * TLEN + t0 - 3) * 32;
    for (int it = tid; it < (ntk + 3) * 8; it += 256) {
        int tl = it >> 3, q = it & 7;
        int t = t0 - 3 + tl;
        float4 v = (t < 0) ? make_float4(0.f, 0.f, 0.f, 0.f)
                           : ((const float4*)(xin))[it];
        s_xi[tl][q * 4 + 0] = v.x;
        s_xi[tl][q * 4 + 1] = v.y;
        s_xi[tl][q * 4 + 2] = v.z;
        s_xi[tl][q * 4 + 3] = v.w;
    }
    __syncthreads();

    // conv4 + silu (same FP order as before: sum taps, then +bias)
    for (int it = tid; it < ntk * 32; it += 256) {
        int j = it >> 5, cc = it & 31;
        float acc = 0.f;
#pragma unroll
        for (int k = 0; k < 4; k++) acc += s_cw[cc * 4 + k] * s_xi[j + k][cc];
        s_xc[j][cc] = siluf(acc + s_cb[cc]);
    }
    __syncthreads();

    // dt0 per token
    if (tid < ntk) {
        float acc = 0.f;
#pragma unroll
        for (int cc = 0; cc < 32; cc++) acc += s_xc[tid][cc] * s_xp[0][cc];
        s_dt0[tid] = acc;
    }
    __syncthreads();

    // emit SC: it = token*96 + e  -> contiguous wave stores
    float* scb = sc + ((size_t)n * TLEN + t0) * 96;
    for (int it = tid; it < ntk * 96; it += 256) {
        int j = it / 96, e = it - j * 96;
        float val;
        if (e < 32) {
            val = s_xc[j][e];
        } else if (e < 64) {
            int d = e - 32;
            val = softplusf(s_dt0[j] * s_dw[d] + s_db[d]);
        } else {
            int r = (e < 80) ? (1 + e - 64) : (17 + e - 80);
            float acc = 0.f;
#pragma unroll
            for (int cc = 0; cc < 32; cc++) acc += s_xc[j][cc] * s_xp[r][cc];
            val = acc;
        }
        scb[it] = val;
    }
}

// -------- phase 2a: per-chunk scan summaries (P = prod a, F = h from 0) -----
__global__ __launch_bounds__(512) void k_scan1(const float* __restrict__ sc,
                                               const float* __restrict__ A_log,
                                               float* __restrict__ Psum,
                                               float* __restrict__ Fsum)
{
    int n = blockIdx.x >> 4;
    int c = blockIdx.x & (NCH - 1);
    int t0 = c * CHUNK;
    int nt = min(CHUNK, TLEN - t0);
    __shared__ float s_sc[CHUNK * 96];
    const float* src = sc + ((size_t)n * TLEN + t0) * 96;
    int nv4 = (nt * 96) >> 2;
    for (int i = threadIdx.x; i < nv4; i += 512)
        ((float4*)s_sc)[i] = ((const float4*)src)[i];
    int tid = threadIdx.x, d = tid >> 4, s = tid & 15;
    float A = -__expf(A_log[tid]);
    __syncthreads();
    float h = 0.f, P = 1.f;
    for (int t = 0; t < nt; t++) {
        const float* p = s_sc + t * 96;
        float dt = p[32 + d], xc = p[d], Bv = p[64 + s];
        float a = __expf(dt * A);
        h = a * h + dt * Bv * xc;
        P *= a;
    }
    size_t idx = ((size_t)n * NCH + c) * 512 + tid;
    Psum[idx] = P;
    Fsum[idx] = h;
}

// -------- phase 2b: combine chunk summaries -> incoming state per chunk -----
__global__ __launch_bounds__(512) void k_comb(const float* __restrict__ Psum,
                                              const float* __restrict__ Fsum,
                                              float* __restrict__ Hin)
{
    int n = blockIdx.x, tid = threadIdx.x;
    const float* pb = Psum + (size_t)n * NCH * 512;
    const float* fb = Fsum + (size_t)n * NCH * 512;
    float* hb = Hin + (size_t)n * NCH * 512;
    float H = 0.f;
#pragma unroll
    for (int c = 0; c < NCH; c++) {
        float P = pb[(size_t)c * 512 + tid];
        float F = fb[(size_t)c * 512 + tid];
        hb[(size_t)c * 512 + tid] = H;
        H = F + P * H;
    }
}

// -------- phase 2c: per-chunk scan with true incoming state, emit y ---------
__global__ __launch_bounds__(512) void k_scan2(const float* __restrict__ sc,
                                               const float* __restrict__ A_log,
                                               const float* __restrict__ Dp,
                                               const float* __restrict__ Hin,
                                               float* __restrict__ yc)  // (NSEQ,TLEN,32)
{
    int n = blockIdx.x >> 4;
    int c = blockIdx.x & (NCH - 1);
    int t0 = c * CHUNK;
    int nt = min(CHUNK, TLEN - t0);
    __shared__ float s_sc[CHUNK * 96];
    __shared__ float s_y[CHUNK * 32];
    const float* src = sc + ((size_t)n * TLEN + t0) * 96;
    int nv4 = (nt * 96) >> 2;
    for (int i = threadIdx.x; i < nv4; i += 512)
        ((float4*)s_sc)[i] = ((const float4*)src)[i];
    int tid = threadIdx.x, d = tid >> 4, s = tid & 15;
    float A = -__expf(A_log[tid]);
    float Dd = Dp[d];
    float h = Hin[((size_t)n * NCH + c) * 512 + tid];
    __syncthreads();
    for (int t = 0; t < nt; t++) {
        const float* p = s_sc + t * 96;
        float dt = p[32 + d], xc = p[d], Bv = p[64 + s], Cv = p[80 + s];
        float a = __expf(dt * A);
        h = a * h + dt * Bv * xc;
        float pp = h * Cv;
        pp += __shfl_xor(pp, 1);
        pp += __shfl_xor(pp, 2);
        pp += __shfl_xor(pp, 4);
        pp += __shfl_xor(pp, 8);
        if (s == 0) s_y[t * 32 + d] = pp + Dd * xc;
    }
    __syncthreads();
    float* yb = yc + ((size_t)n * TLEN + t0) * 32;
    int ny4 = (nt * 32) >> 2;
    for (int i = threadIdx.x; i < ny4; i += 512)
        ((float4*)yb)[i] = ((const float4*)s_y)[i];
}

// ---------------- phase 3: gate + out-proj + scatter ------------------------
template <int MODE>
__global__ void k_p3(const float* __restrict__ yc, const float* __restrict__ Zb,
                     const float* __restrict__ out_w,  // (16,32)
                     float* __restrict__ out)
{
    __shared__ float s_w[16 * 32];
    for (int i = threadIdx.x; i < 512; i += blockDim.x) s_w[i] = out_w[i];
    __syncthreads();
    int tid = blockIdx.x * blockDim.x + threadIdx.x;
    if (tid >= NSEQ * LSEQ) return;
    int n = tid >> 10, l = tid & 1023, t = l + 1;
    const float* y = yc + ((size_t)n * TLEN + t) * 32;
    const float* z = Zb + ((size_t)n * TLEN + t) * 32;
    float yv[32];
#pragma unroll
    for (int c = 0; c < 32; c++) yv[c] = y[c] * siluf(z[c]);
    float o[16];
#pragma unroll
    for (int j = 0; j < 16; j++) {
        float acc = 0.f;
#pragma unroll
        for (int c = 0; c < 32; c++) acc += yv[c] * s_w[j * 32 + c];
        o[j] = acc * (1.0f / 3.0f);
    }
    int b = n >> 6, cube = n & 63;
    if (MODE == 0) {
        int i2 = l >> 5, j2 = l & 31;
        int io = i2 >> 1, jo = j2 >> 1;
        int coff = ((i2 & 1) << 1) | (j2 & 1);
#pragma unroll
        for (int j = 0; j < 16; j++) out[oidx(b, cube, j * 4 + coff, io, jo)] = o[j];
    } else if (MODE == 1) {
        int c = l >> 4, jj = l & 15;
#pragma unroll
        for (int j = 0; j < 16; j++) out[oidx(b, cube, c, j, jj)] += o[j];
    } else {
        int c = l >> 4, ii = l & 15;
#pragma unroll
        for (int j = 0; j < 16; j++) out[oidx(b, cube, c, ii, j)] += o[j];
    }
}

}  // namespace

extern "C" void kernel_launch(void* const* d_in, const int* in_sizes, int n_in,
                              void* d_out, int out_size, void* d_ws, size_t ws_size,
                              hipStream_t stream) {
    const float* x   = (const float*)d_in[0];
    const float* gt1 = (const float*)d_in[1];
    const float* gt2 = (const float*)d_in[2];
    const float* ln1g = (const float*)d_in[3];
    const float* ln1b = (const float*)d_in[4];
    const float* ln2g = (const float*)d_in[5];
    const float* ln2b = (const float*)d_in[6];
    const float* m[2][9];
    for (int mi = 0; mi < 2; mi++)
        for (int k = 0; k < 9; k++) m[mi][k] = (const float*)d_in[7 + mi * 9 + k];
    float* out = (float*)d_out;

    float* ws = (float*)d_ws;
    float* XI = ws;                               // 128*1025*32 (16.8 MB)
    float* ZB = XI + (size_t)NSEQ * TLEN * 32;    // 16.8 MB
    float* SC = ZB + (size_t)NSEQ * TLEN * 32;    // 128*1025*96 (50.4 MB)
    float* YC = SC + (size_t)NSEQ * TLEN * 96;    // 16.8 MB
    float* PS = YC + (size_t)NSEQ * TLEN * 32;    // 4.2 MB
    float* FS = PS + (size_t)NSEQ * NCH * 512;    // 4.2 MB
    float* HI = FS + (size_t)NSEQ * NCH * 512;    // 4.2 MB

    dim3 btile(256), gtile(NSEQ * NT);
    dim3 gscan(NSEQ * NCH), bscan(512);
    dim3 grd3((NSEQ * LSEQ + 255) / 256);

    for (int mode = 0; mode < 3; mode++) {
        int pi = (mode == 0) ? 0 : 1;
        const float* gt = (mode == 0) ? gt1 : gt2;
        const float* lg = (mode == 0) ? ln1g : ln2g;
        const float* lb = (mode == 0) ? ln1b : ln2b;
        const float* const* P = m[pi];
        // P: 0 in_w, 1 conv_w, 2 conv_b, 3 xproj_w, 4 dt_w, 5 dt_b, 6 A_log, 7 D, 8 out_w
        if (mode == 0)      k_p1a<0><<<gtile, btile, 0, stream>>>(x, gt, lg, lb, P[0], XI, ZB);
        else if (mode == 1) k_p1a<1><<<gtile, btile, 0, stream>>>(x, gt, lg, lb, P[0], XI, ZB);
        else                k_p1a<2><<<gtile, btile, 0, stream>>>(x, gt, lg, lb, P[0], XI, ZB);
        k_p1b<<<gtile, btile, 0, stream>>>(XI, P[1], P[2], P[3], P[4], P[5], SC);
        k_scan1<<<gscan, bscan, 0, stream>>>(SC, P[6], PS, FS);
        k_comb<<<dim3(NSEQ), bscan, 0, stream>>>(PS, FS, HI);
        k_scan2<<<gscan, bscan, 0, stream>>>(SC, P[6], P[7], HI, YC);
        if (mode == 0)      k_p3<0><<<grd3, btile, 0, stream>>>(YC, ZB, P[8], out);
        else if (mode == 1) k_p3<1><<<grd3, btile, 0, stream>>>(YC, ZB, P[8], out);
        else                k_p3<2><<<grd3, btile, 0, stream>>>(YC, ZB, P[8], out);
    }
}